// Round 7
// baseline (1813.071 us; speedup 1.0000x reference)
//
#include <hip/hip_runtime.h>
#include <math.h>

// ---------------- problem constants ----------------
#define BQ    1024
#define NB    131072
#define DS    64
#define DF    256
#define KSEL  16

// ---------------- score kernel tiling ----------------
#define QT    128        // queries per block (4 waves x 32)
#define BC    64         // blobs per chunk
#define PCH   64         // chunk stripes (grid.x)
#define NCHUNK (NB / BC)             // 2048
#define CHUNKS_PER_BLK (NCHUNK/PCH)  // 32
#define SLD   68                     // slot leading dim (floats, 272B rows, 16B-aligned)
#define NSLOT 16                     // survivor-row slots (one 16-row batch)

// Bprep layout per chunk: [split(2)][ntile(4)][kstep(4)][lane(64)][16B] = 32 KB
#define CH_BYTES   32768
#define SPLIT_OFF  16384

typedef __bf16 bf16x8 __attribute__((ext_vector_type(8)));
typedef float  f32x4  __attribute__((ext_vector_type(4)));
typedef unsigned long long u64;

#define ENC_NEGINF 0x007FFFFFu   // map_f32(-inf)

__device__ __forceinline__ unsigned map_f32(float s) {
    unsigned u = __float_as_uint(s);
    return (u & 0x80000000u) ? ~u : (u | 0x80000000u);
}

__device__ __forceinline__ float unmap_f32(unsigned e) {
    return __uint_as_float((e & 0x80000000u) ? (e & 0x7FFFFFFFu) : ~e);
}

__device__ __forceinline__ void async_cp16(const void* g, void* l) {
    __builtin_amdgcn_global_load_lds(
        (const __attribute__((address_space(1))) unsigned int*)g,
        (__attribute__((address_space(3))) unsigned int*)l, 16, 0, 0);
}

// ---------------- fused preprocess: fragments + m2 + log-alpha ----------------
__global__ __launch_bounds__(256)
void prep_kernel(const float* __restrict__ mu,
                 const float* __restrict__ log_var,
                 const float* __restrict__ raw_alpha,
                 char* __restrict__ bprep,
                 float* __restrict__ m2la,
                 unsigned* __restrict__ gcut)
{
    int gid  = blockIdx.x * 256 + threadIdx.x;   // NB*8 = 2^20 threads
    if (gid < BQ) gcut[gid] = ENC_NEGINF;        // re-init global cutoffs each launch
    int blob = gid >> 3;
    int dd   = gid & 7;

    const float* mrow = mu      + (size_t)blob * DS + dd * 8;
    const float* vrow = log_var + (size_t)blob * DS + dd * 8;
    float4 ma = ((const float4*)mrow)[0], mb = ((const float4*)mrow)[1];
    float4 va = ((const float4*)vrow)[0], vb = ((const float4*)vrow)[1];
    float m[8] = {ma.x, ma.y, ma.z, ma.w, mb.x, mb.y, mb.z, mb.w};
    float lv[8] = {va.x, va.y, va.z, va.w, vb.x, vb.y, vb.z, vb.w};

    bf16x8 hiv, liv, hmv, lmv;
    float p = 0.0f;
    #pragma unroll
    for (int j = 0; j < 8; ++j) {
        float iv = __expf(-lv[j]);
        float mv = m[j] * iv;
        p += m[j] * mv;
        __bf16 h1 = (__bf16)iv;  hiv[j] = h1; liv[j] = (__bf16)(iv - (float)h1);
        __bf16 h2 = (__bf16)mv;  hmv[j] = h2; lmv[j] = (__bf16)(mv - (float)h2);
    }
    p += __shfl_xor(p, 1);
    p += __shfl_xor(p, 2);
    p += __shfl_xor(p, 4);

    int c  = blob >> 6;
    int nt = (blob >> 4) & 3;
    int bl = blob & 15;
    int lane  = (dd & 3) * 16 + bl;
    int ks_iv = dd >> 2;            // k = dd*8      (iv rows: k in [0,64))
    int ks_mv = 2 + (dd >> 2);      // k = 64+dd*8   (mu*iv rows)
    size_t b_iv = (size_t)c * CH_BYTES + nt * 4096 + ks_iv * 1024 + lane * 16;
    size_t b_mv = (size_t)c * CH_BYTES + nt * 4096 + ks_mv * 1024 + lane * 16;
    *(bf16x8*)(bprep + b_iv)             = hiv;
    *(bf16x8*)(bprep + b_iv + SPLIT_OFF) = liv;
    *(bf16x8*)(bprep + b_mv)             = hmv;
    *(bf16x8*)(bprep + b_mv + SPLIT_OFF) = lmv;

    if (dd == 0) {
        m2la[blob * 2]     = p;
        m2la[blob * 2 + 1] = -log1pf(__expf(-raw_alpha[blob]));  // log sigmoid
    }
}

// ---------------- register top-16 insertion (tree argmin, unsorted) ----------------
__device__ __forceinline__ void ins16(float (&ts)[16], int (&ti)[16],
                                      float& mymin, float s, int idx)
{
    float v0[8]; int j0[8];
    #pragma unroll
    for (int i = 0; i < 8; ++i) {
        bool b = ts[2*i+1] < ts[2*i];
        v0[i] = b ? ts[2*i+1] : ts[2*i];
        j0[i] = (i << 1) | (b ? 1 : 0);
    }
    float v1[4]; int j1[4];
    #pragma unroll
    for (int i = 0; i < 4; ++i) {
        bool b = v0[2*i+1] < v0[2*i];
        v1[i] = b ? v0[2*i+1] : v0[2*i];
        j1[i] = b ? j0[2*i+1] : j0[2*i];
    }
    float v2[2]; int j2[2];
    #pragma unroll
    for (int i = 0; i < 2; ++i) {
        bool b = v1[2*i+1] < v1[2*i];
        v2[i] = b ? v1[2*i+1] : v1[2*i];
        j2[i] = b ? j1[2*i+1] : j1[2*i];
    }
    int am = (v2[1] < v2[0]) ? j2[1] : j2[0];
    #pragma unroll
    for (int i = 0; i < 16; ++i) {
        bool b = (i == am);
        ts[i] = b ? s : ts[i];
        ti[i] = b ? idx : ti[i];
    }
    float n0[8];
    #pragma unroll
    for (int i = 0; i < 8; ++i) n0[i] = fminf(ts[2*i], ts[2*i+1]);
    float n1[4];
    #pragma unroll
    for (int i = 0; i < 4; ++i) n1[i] = fminf(n0[2*i], n0[2*i+1]);
    mymin = fminf(fminf(n1[0], n1[1]), fminf(n1[2], n1[3]));
}

// ---------------- score + top-k kernel ----------------
// In-register row screen (16-lane shuffle max vs stale-monotone cutF).
// Surviving rows flushed via 8 deterministic 16-row batches; the batch loop
// is FULLY UNROLLED so all acc[] indices are compile-time (rule #20: runtime
// indexing sent acc to scratch in R6 -> 683 MB HBM spill traffic).
// __launch_bounds__(256,2): grid is 512 blocks = 2/CU max, so capping VGPR
// below live state (R6's (256,3) -> 84 VGPR) only caused spills.
__global__ __launch_bounds__(256, 2)
void score_topk_kernel(const float* __restrict__ query,
                       const char* __restrict__ bprep,
                       const float* __restrict__ m2la,
                       const float* __restrict__ log_tau_p,
                       u64* __restrict__ cand,
                       unsigned* __restrict__ gcut)
{
    __shared__ __align__(16) short Bs[CH_BYTES / 2];      // 32 KB fragment buffer
    __shared__ __align__(16) float slotbuf[NSLOT][SLD];   // 4.25 KB batch rows
    __shared__ __align__(16) float cutF[QT];              // per-row cutoff (stale, monotone)
    __shared__ int bmask[8][4];                           // per-batch per-quad survivor nibbles
    __shared__ unsigned actmask;                          // active-batch bits

    const int tid   = threadIdx.x;
    const int lane  = tid & 63;
    const int quad  = lane >> 4;
    const int mrow  = lane & 15;
    const int wv    = tid >> 6;
    const int qbase = blockIdx.y * QT;
    const int qloc  = tid & (QT - 1);
    const bool owner = tid < QT;

    const float nhit = -0.5f * expf(-log_tau_p[0]);

    // ---- build persistent A fragments (hi+lo) in registers ----
    bf16x8 ahi[2][4], alo[2][4];
    #pragma unroll
    for (int mt = 0; mt < 2; ++mt) {
        const float* qrow = query + (size_t)(qbase + wv * 32 + mt * 16 + mrow) * DS;
        #pragma unroll
        for (int ks = 0; ks < 4; ++ks) {
            int kq = ks * 32 + quad * 8;
            int d0 = kq & 63;
            bool lin = kq >= 64;
            bf16x8 h, l;
            #pragma unroll
            for (int j = 0; j < 8; ++j) {
                float v = qrow[d0 + j];
                float x = lin ? (-2.0f * v) : (v * v);
                __bf16 hb = (__bf16)x;
                h[j] = hb;
                l[j] = (__bf16)(x - (float)hb);
            }
            ahi[mt][ks] = h; alo[mt][ks] = l;
        }
    }

    // ---- owner state: thread tid<QT owns query row tid ----
    float ts[16]; int ti[16];
    #pragma unroll
    for (int i = 0; i < 16; ++i) { ts[i] = -INFINITY; ti[i] = 0; }
    float mymin = -INFINITY;
    unsigned* const gslot = gcut + qbase + qloc;

    if (tid < QT) cutF[tid] = -INFINITY;
    if (tid == 0) actmask = 0;

    const char* BsB = (const char*)Bs;

    // ---- stage first chunk ----
    int c = blockIdx.x;
    {
        const char* src = bprep + (size_t)c * CH_BYTES;
        #pragma unroll
        for (int i = 0; i < 8; ++i) {
            int s = tid + i * 256;
            async_cp16(src + s * 16, (void*)(BsB + s * 16));
        }
    }
    __syncthreads();   // Bs ready; LDS init visible

    for (int it = 0; it < CHUNKS_PER_BLK; ++it) {
        const int nbase = c * BC;
        const int cn    = c + PCH;
        const bool more = (it + 1) < CHUNKS_PER_BLK;

        // owners publish 16th-best AND fetch freshest global cutoff (one RMW);
        // latency hides under the MFMA phase.
        unsigned eg = ENC_NEGINF;
        if (owner) eg = atomicMax(gslot, map_f32(mymin));

        float2 ml[4];
        #pragma unroll
        for (int nt = 0; nt < 4; ++nt)
            ml[nt] = *(const float2*)&m2la[(size_t)(nbase + nt * 16 + mrow) * 2];

        // ---- MFMA: 4 ntiles x 2 mtiles x 4 ksteps x 3 products ----
        f32x4 acc[2][4];
        #pragma unroll
        for (int nt = 0; nt < 4; ++nt) {
            bf16x8 bh[4], bl[4];
            #pragma unroll
            for (int ks = 0; ks < 4; ++ks) {
                bh[ks] = *(const bf16x8*)(BsB + nt * 4096 + ks * 1024 + lane * 16);
                bl[ks] = *(const bf16x8*)(BsB + SPLIT_OFF + nt * 4096 + ks * 1024 + lane * 16);
            }
            #pragma unroll
            for (int mt = 0; mt < 2; ++mt) {
                f32x4 a = {0.0f, 0.0f, 0.0f, 0.0f};
                #pragma unroll
                for (int ks = 0; ks < 4; ++ks) {
                    a = __builtin_amdgcn_mfma_f32_16x16x32_bf16(ahi[mt][ks], bh[ks], a, 0, 0, 0);
                    a = __builtin_amdgcn_mfma_f32_16x16x32_bf16(ahi[mt][ks], bl[ks], a, 0, 0, 0);
                    a = __builtin_amdgcn_mfma_f32_16x16x32_bf16(alo[mt][ks], bh[ks], a, 0, 0, 0);
                }
                acc[mt][nt] = a;
            }
        }
        __syncthreads();   // B1: frag reads done; Bs reusable; prev-iter cutF visible

        if (more) {
            const char* src = bprep + (size_t)cn * CH_BYTES;
            #pragma unroll
            for (int i = 0; i < 8; ++i) {
                int s = tid + i * 256;
                async_cp16(src + s * 16, (void*)(BsB + s * 16));
            }
        }

        // ---- transform scores in regs; in-register row screen ----
        float rmax[8];
        #pragma unroll
        for (int mt = 0; mt < 2; ++mt)
            #pragma unroll
            for (int nt = 0; nt < 4; ++nt) {
                float m2 = ml[nt].x, la = ml[nt].y;
                #pragma unroll
                for (int reg = 0; reg < 4; ++reg)
                    acc[mt][nt][reg] = nhit * (acc[mt][nt][reg] + m2) + la;
            }
        #pragma unroll
        for (int mt = 0; mt < 2; ++mt)
            #pragma unroll
            for (int reg = 0; reg < 4; ++reg)
                rmax[mt * 4 + reg] = fmaxf(fmaxf(acc[mt][0][reg], acc[mt][1][reg]),
                                           fmaxf(acc[mt][2][reg], acc[mt][3][reg]));
        #pragma unroll
        for (int off = 1; off < 16; off <<= 1)
            #pragma unroll
            for (int i = 0; i < 8; ++i)
                rmax[i] = fmaxf(rmax[i], __shfl_xor(rmax[i], off));
        // rows this group feeds: wv*32 + mt*16 + quad*4 + reg (batch wv*2+mt)
        f32x4 c0 = *(const f32x4*)&cutF[wv * 32 + quad * 4];
        f32x4 c1 = *(const f32x4*)&cutF[wv * 32 + 16 + quad * 4];
        unsigned pend = 0;
        #pragma unroll
        for (int i = 0; i < 4; ++i) {
            if (rmax[i]     > c0[i]) pend |= (1u << i);
            if (rmax[4 + i] > c1[i]) pend |= (1u << (4 + i));
        }
        // one writer per bmask cell; actmask via atomicOr (survivors only)
        if (mrow == 0) {
            bmask[wv * 2][quad]     = (int)(pend & 15u);
            bmask[wv * 2 + 1][quad] = (int)((pend >> 4) & 15u);
            unsigned ab = 0;
            if (pend & 15u)  ab |= 1u << (wv * 2);
            if (pend >> 4)   ab |= 1u << (wv * 2 + 1);
            if (ab) atomicOr(&actmask, ab);
        }
        __syncthreads();   // B2: bmask/actmask visible; prefetch vmcnt drained

        const unsigned am = actmask;    // block-uniform (no writes until reset)
        const float gc = unmap_f32(eg);

        // ---- deterministic batch flush: FULLY UNROLLED (b compile-time) ----
        #pragma unroll
        for (int b = 0; b < 8; ++b) {
            if ((am >> b) & 1u) {                // uniform condition
                if (wv == (b >> 1)) {            // owning wave writes all 16 rows
                    #pragma unroll
                    for (int reg = 0; reg < 4; ++reg)
                        #pragma unroll
                        for (int nt = 0; nt < 4; ++nt)
                            slotbuf[quad * 4 + reg][nt * 16 + mrow] = acc[b & 1][nt][reg];
                }
                __syncthreads();                 // batch rows ready
                if (owner && (qloc >> 4) == b) {
                    int r = qloc & 15;
                    if ((bmask[b][r >> 2] >> (r & 3)) & 1) {
                        float cut = fmaxf(mymin, gc);
                        const float* rowp = &slotbuf[r][0];
                        unsigned gm = 0u;
                        #pragma unroll
                        for (int i = 0; i < 16; ++i) {
                            float4 v = ((const float4*)rowp)[i];
                            float m4 = fmaxf(fmaxf(v.x, v.y), fmaxf(v.z, v.w));
                            if (m4 > cut) gm |= (1u << i);
                        }
                        while (gm) {
                            int i = __ffs(gm) - 1; gm &= gm - 1u;
                            float4 v = ((const float4*)rowp)[i];
                            int b0 = nbase + i * 4;
                            if (v.x > cut) { ins16(ts, ti, mymin, v.x, b0);     cut = fmaxf(mymin, gc); }
                            if (v.y > cut) { ins16(ts, ti, mymin, v.y, b0 + 1); cut = fmaxf(mymin, gc); }
                            if (v.z > cut) { ins16(ts, ti, mymin, v.z, b0 + 2); cut = fmaxf(mymin, gc); }
                            if (v.w > cut) { ins16(ts, ti, mymin, v.w, b0 + 3); cut = fmaxf(mymin, gc); }
                        }
                    }
                }
                __syncthreads();                 // scans done before slot reuse
            }
        }

        if (owner) cutF[qloc] = fmaxf(mymin, gc);   // next-iter screen (monotone)
        if (tid == 0) actmask = 0;
        __syncthreads();   // B3: cutF/actmask settled; prefetched Bs ready
        c = cn;
    }

    // ---- owners write their block-top-16 directly (coalesced 128B rows) ----
    if (owner) {
        u64* dst = cand + ((size_t)blockIdx.x * BQ + qbase + qloc) * KSEL;
        #pragma unroll
        for (int r = 0; r < KSEL; ++r)
            dst[r] = ((u64)map_f32(ts[r]) << 32) | (u64)(0xFFFFFFFFu - (unsigned)ti[r]);
    }
}

// ---------------- global merge + exact recompute + compositing ----------------
__global__ __launch_bounds__(256)
void merge_composite_kernel(const float* __restrict__ query,
                            const float* __restrict__ mu,
                            const float* __restrict__ log_var,
                            const float* __restrict__ raw_alpha,
                            const float* __restrict__ features,
                            const float* __restrict__ log_tau_p,
                            const u64* __restrict__ cand,
                            float* __restrict__ out)
{
    const int q   = blockIdx.x;
    const int tid = threadIdx.x;
    const int wv = tid >> 6, lane = tid & 63;

    __shared__ u64   wtop[4 * KSEL];
    __shared__ int   sel[KSEL];
    __shared__ float w_sh[KSEL];
    __shared__ float mah[KSEL];
    __shared__ float alp[KSEL];

    // 1024 keys in [stripe][query][16] layout: each wave owns 256 consecutive ids
    u64 k[4];
    #pragma unroll
    for (int r = 0; r < 4; ++r) {
        int g = wv * 256 + r * 64 + lane;
        k[r] = cand[((size_t)(g >> 4) * BQ + q) * KSEL + (g & 15)];
    }

    // wave-local top-16 (no barriers)
    for (int r = 0; r < KSEL; ++r) {
        u64 m = k[0];
        #pragma unroll
        for (int j = 1; j < 4; ++j) if (k[j] > m) m = k[j];
        #pragma unroll
        for (int off = 32; off > 0; off >>= 1) {
            unsigned hi = __shfl_xor((unsigned)(m >> 32), off);
            unsigned lo = __shfl_xor((unsigned)(m & 0xFFFFFFFFu), off);
            u64 o = ((u64)hi << 32) | lo;
            if (o > m) m = o;
        }
        if (lane == 0) wtop[wv * KSEL + r] = m;
        #pragma unroll
        for (int j = 0; j < 4; ++j) if (k[j] == m) k[j] = 0ull;  // keys unique
    }
    __syncthreads();

    // wave 0: merge 64 -> 16 (shuffle argmax rounds)
    if (wv == 0) {
        u64 kk = wtop[lane];
        for (int r = 0; r < KSEL; ++r) {
            u64 m = kk;
            #pragma unroll
            for (int off = 32; off > 0; off >>= 1) {
                unsigned hi = __shfl_xor((unsigned)(m >> 32), off);
                unsigned lo = __shfl_xor((unsigned)(m & 0xFFFFFFFFu), off);
                u64 o = ((u64)hi << 32) | lo;
                if (o > m) m = o;
            }
            if (kk == m) kk = 0ull;
            if (lane == 0)
                sel[r] = (int)(0xFFFFFFFFu - (unsigned)(m & 0xFFFFFFFFull));
        }
    }
    __syncthreads();

    // exact mahal per selected blob (direct gathered form, like reference)
    for (int r = wv; r < KSEL; r += 4) {
        int bi = sel[r];
        float qd = query[(size_t)q * DS + lane];
        float mv = mu[(size_t)bi * DS + lane];
        float d  = qd - mv;
        float t  = d * d * expf(-log_var[(size_t)bi * DS + lane]);
        #pragma unroll
        for (int off = 32; off > 0; off >>= 1) t += __shfl_down(t, off);
        if (lane == 0) {
            mah[r] = t;
            alp[r] = 1.0f / (1.0f + expf(-raw_alpha[bi]));
        }
    }
    __syncthreads();

    if (tid == 0) {
        float tau = expf(log_tau_p[0]);
        float cap = 0.3f / 16.0f;
        float logT = 0.0f;
        for (int r = 0; r < KSEL; ++r) {
            float K   = expf(-0.5f * mah[r] / tau);
            float eff = fminf(alp[r] * K, cap);
            w_sh[r]   = eff * expf(logT);
            logT     += log1pf(-fminf(eff, 1.0f - 1e-6f));
        }
        out[(size_t)BQ * DF + q] = expf(logT);
    }
    __syncthreads();

    {
        float a = 0.0f;
        #pragma unroll
        for (int r = 0; r < KSEL; ++r)
            a += w_sh[r] * features[(size_t)sel[r] * DF + tid];
        out[(size_t)q * DF + tid] = a;
    }
}

// ---------------- launch ----------------
extern "C" void kernel_launch(void* const* d_in, const int* in_sizes, int n_in,
                              void* d_out, int out_size, void* d_ws, size_t ws_size,
                              hipStream_t stream)
{
    (void)in_sizes; (void)n_in; (void)out_size; (void)ws_size;
    const float* query     = (const float*)d_in[0];
    const float* mu        = (const float*)d_in[1];
    const float* log_var   = (const float*)d_in[2];
    const float* raw_alpha = (const float*)d_in[3];
    const float* features  = (const float*)d_in[4];
    const float* log_tau   = (const float*)d_in[5];
    float* out = (float*)d_out;

    // ws layout: Bprep 64 MB | m2la 1 MB | cand 8 MB
    char*  bprep = (char*)d_ws;
    float* m2la  = (float*)((char*)d_ws + (size_t)NCHUNK * CH_BYTES);
    u64*   cand  = (u64*)((char*)d_ws + (size_t)NCHUNK * CH_BYTES + (size_t)NB * 2 * 4);
    // global per-query cutoffs: borrow the t_residual tail of `out` (4 KB);
    // merge_composite_kernel fully overwrites it afterwards.
    unsigned* gcut = (unsigned*)(out + (size_t)BQ * DF);

    prep_kernel<<<(NB * 8) / 256, 256, 0, stream>>>(mu, log_var, raw_alpha, bprep, m2la, gcut);

    dim3 g2(PCH, BQ / QT);
    score_topk_kernel<<<g2, 256, 0, stream>>>(query, bprep, m2la, log_tau, cand, gcut);

    merge_composite_kernel<<<BQ, 256, 0, stream>>>(query, mu, log_var, raw_alpha,
                                                   features, log_tau, cand, out);
}

// Round 8
// 622.187 us; speedup vs baseline: 2.9140x; 2.9140x over previous
//
#include <hip/hip_runtime.h>
#include <math.h>

// ---------------- problem constants ----------------
#define BQ    1024
#define NB    131072
#define DS    64
#define DF    256
#define KSEL  16

// ---------------- score kernel tiling ----------------
#define QT    128        // queries per block (4 waves x 32)
#define BC    64         // blobs per chunk
#define PCH   64         // chunk stripes (grid.x)
#define NCHUNK (NB / BC)             // 2048
#define CHUNKS_PER_BLK (NCHUNK/PCH)  // 32

// Bprep layout per chunk: [split(2)][ntile(4)][kstep(4)][lane(64)][16B] = 32 KB
#define CH_BYTES   32768
#define SPLIT_OFF  16384

typedef __bf16 bf16x8 __attribute__((ext_vector_type(8)));
typedef float  f32x4  __attribute__((ext_vector_type(4)));
typedef unsigned long long u64;

#define ENC_NEGINF 0x007FFFFFu   // map_f32(-inf)

__device__ __forceinline__ unsigned map_f32(float s) {
    unsigned u = __float_as_uint(s);
    return (u & 0x80000000u) ? ~u : (u | 0x80000000u);
}

__device__ __forceinline__ float unmap_f32(unsigned e) {
    return __uint_as_float((e & 0x80000000u) ? (e & 0x7FFFFFFFu) : ~e);
}

__device__ __forceinline__ void async_cp16(const void* g, void* l) {
    __builtin_amdgcn_global_load_lds(
        (const __attribute__((address_space(1))) unsigned int*)g,
        (__attribute__((address_space(3))) unsigned int*)l, 16, 0, 0);
}

// ---------------- fused preprocess: fragments + m2 + log-alpha ----------------
__global__ __launch_bounds__(256)
void prep_kernel(const float* __restrict__ mu,
                 const float* __restrict__ log_var,
                 const float* __restrict__ raw_alpha,
                 char* __restrict__ bprep,
                 float* __restrict__ m2la,
                 unsigned* __restrict__ gcut)
{
    int gid  = blockIdx.x * 256 + threadIdx.x;   // NB*8 = 2^20 threads
    if (gid < BQ) gcut[gid] = ENC_NEGINF;        // re-init global cutoffs each launch
    int blob = gid >> 3;
    int dd   = gid & 7;

    const float* mrow = mu      + (size_t)blob * DS + dd * 8;
    const float* vrow = log_var + (size_t)blob * DS + dd * 8;
    float4 ma = ((const float4*)mrow)[0], mb = ((const float4*)mrow)[1];
    float4 va = ((const float4*)vrow)[0], vb = ((const float4*)vrow)[1];
    float m[8] = {ma.x, ma.y, ma.z, ma.w, mb.x, mb.y, mb.z, mb.w};
    float lv[8] = {va.x, va.y, va.z, va.w, vb.x, vb.y, vb.z, vb.w};

    bf16x8 hiv, liv, hmv, lmv;
    float p = 0.0f;
    #pragma unroll
    for (int j = 0; j < 8; ++j) {
        float iv = __expf(-lv[j]);
        float mv = m[j] * iv;
        p += m[j] * mv;
        __bf16 h1 = (__bf16)iv;  hiv[j] = h1; liv[j] = (__bf16)(iv - (float)h1);
        __bf16 h2 = (__bf16)mv;  hmv[j] = h2; lmv[j] = (__bf16)(mv - (float)h2);
    }
    p += __shfl_xor(p, 1);
    p += __shfl_xor(p, 2);
    p += __shfl_xor(p, 4);

    int c  = blob >> 6;
    int nt = (blob >> 4) & 3;
    int bl = blob & 15;
    int lane  = (dd & 3) * 16 + bl;
    int ks_iv = dd >> 2;            // k = dd*8      (iv rows: k in [0,64))
    int ks_mv = 2 + (dd >> 2);      // k = 64+dd*8   (mu*iv rows)
    size_t b_iv = (size_t)c * CH_BYTES + nt * 4096 + ks_iv * 1024 + lane * 16;
    size_t b_mv = (size_t)c * CH_BYTES + nt * 4096 + ks_mv * 1024 + lane * 16;
    *(bf16x8*)(bprep + b_iv)             = hiv;
    *(bf16x8*)(bprep + b_iv + SPLIT_OFF) = liv;
    *(bf16x8*)(bprep + b_mv)             = hmv;
    *(bf16x8*)(bprep + b_mv + SPLIT_OFF) = lmv;

    if (dd == 0) {
        m2la[blob * 2]     = p;
        m2la[blob * 2 + 1] = -log1pf(__expf(-raw_alpha[blob]));  // log sigmoid
    }
}

// ---------------- register top-16 insertion (tree argmin, unsorted) ----------------
__device__ __forceinline__ void ins16(float (&ts)[16], int (&ti)[16],
                                      float& mymin, float s, int idx)
{
    float v0[8]; int j0[8];
    #pragma unroll
    for (int i = 0; i < 8; ++i) {
        bool b = ts[2*i+1] < ts[2*i];
        v0[i] = b ? ts[2*i+1] : ts[2*i];
        j0[i] = (i << 1) | (b ? 1 : 0);
    }
    float v1[4]; int j1[4];
    #pragma unroll
    for (int i = 0; i < 4; ++i) {
        bool b = v0[2*i+1] < v0[2*i];
        v1[i] = b ? v0[2*i+1] : v0[2*i];
        j1[i] = b ? j0[2*i+1] : j0[2*i];
    }
    float v2[2]; int j2[2];
    #pragma unroll
    for (int i = 0; i < 2; ++i) {
        bool b = v1[2*i+1] < v1[2*i];
        v2[i] = b ? v1[2*i+1] : v1[2*i];
        j2[i] = b ? j1[2*i+1] : j1[2*i];
    }
    int am = (v2[1] < v2[0]) ? j2[1] : j2[0];
    #pragma unroll
    for (int i = 0; i < 16; ++i) {
        bool b = (i == am);
        ts[i] = b ? s : ts[i];
        ti[i] = b ? idx : ti[i];
    }
    float n0[8];
    #pragma unroll
    for (int i = 0; i < 8; ++i) n0[i] = fminf(ts[2*i], ts[2*i+1]);
    float n1[4];
    #pragma unroll
    for (int i = 0; i < 4; ++i) n1[i] = fminf(n0[2*i], n0[2*i+1]);
    mymin = fminf(fminf(n1[0], n1[1]), fminf(n1[2], n1[3]));
}

// static 16:1 mux over acc[4] f32x4 (no runtime array indexing -> no scratch)
__device__ __forceinline__ float mux16(const f32x4 (&a)[4], int i)
{
    float v = a[0][0];
    v = (i == 1)  ? a[0][1] : v;  v = (i == 2)  ? a[0][2] : v;  v = (i == 3)  ? a[0][3] : v;
    v = (i == 4)  ? a[1][0] : v;  v = (i == 5)  ? a[1][1] : v;  v = (i == 6)  ? a[1][2] : v;
    v = (i == 7)  ? a[1][3] : v;  v = (i == 8)  ? a[2][0] : v;  v = (i == 9)  ? a[2][1] : v;
    v = (i == 10) ? a[2][2] : v;  v = (i == 11) ? a[2][3] : v;  v = (i == 12) ? a[3][0] : v;
    v = (i == 13) ? a[3][1] : v;  v = (i == 14) ? a[3][2] : v;  v = (i == 15) ? a[3][3] : v;
    return v;
}

__device__ __forceinline__ u64 shflxor64(u64 m, int mask)
{
    unsigned hi = __shfl_xor((unsigned)(m >> 32), mask);
    unsigned lo = __shfl_xor((unsigned)(m & 0xFFFFFFFFu), mask);
    return ((u64)hi << 32) | lo;
}

// ---------------- score + top-k kernel ----------------
// SWAPPED MFMA operands: mfma(blob_frag, query_frag) -> D[blob][query].
// Each lane holds, per mt, 16 scores of ONE query (col = lane&15); the 4-lane
// team (lane, +16, +32, +48) covers that query's 64 blobs per chunk. All
// screening / top-16 maintenance is register-resident: no score tile in LDS,
// no transpose scan, no half-stream merge. 2 barriers/iter (was 3).
__global__ __launch_bounds__(256, 2)
void score_topk_kernel(const float* __restrict__ query,
                       const char* __restrict__ bprep,
                       const float* __restrict__ m2la,
                       const float* __restrict__ log_tau_p,
                       u64* __restrict__ cand,
                       unsigned* __restrict__ gcut)
{
    __shared__ __align__(16) short Bs[CH_BYTES / 2];   // 32 KB fragment buffer

    const int tid   = threadIdx.x;
    const int lane  = tid & 63;
    const int quad  = lane >> 4;
    const int mrow  = lane & 15;
    const int wv    = tid >> 6;
    const int qbase = blockIdx.y * QT;

    const float nhit = -0.5f * expf(-log_tau_p[0]);

    // ---- build persistent query fragments (hi+lo) in registers ----
    // (unchanged layout: row index = mrow, k-chunk = quad*8 within each ks)
    bf16x8 ahi[2][4], alo[2][4];
    #pragma unroll
    for (int mt = 0; mt < 2; ++mt) {
        const float* qrow = query + (size_t)(qbase + wv * 32 + mt * 16 + mrow) * DS;
        #pragma unroll
        for (int ks = 0; ks < 4; ++ks) {
            int kq = ks * 32 + quad * 8;
            int d0 = kq & 63;
            bool lin = kq >= 64;
            bf16x8 h, l;
            #pragma unroll
            for (int j = 0; j < 8; ++j) {
                float v = qrow[d0 + j];
                float x = lin ? (-2.0f * v) : (v * v);
                __bf16 hb = (__bf16)x;
                h[j] = hb;
                l[j] = (__bf16)(x - (float)hb);
            }
            ahi[mt][ks] = h; alo[mt][ks] = l;
        }
    }

    // ---- per-lane top-16 state for the lane's two queries ----
    float ts0[16], ts1[16]; int ti0[16], ti1[16];
    #pragma unroll
    for (int i = 0; i < 16; ++i) {
        ts0[i] = -INFINITY; ti0[i] = 0;
        ts1[i] = -INFINITY; ti1[i] = 0;
    }
    float my0 = -INFINITY, my1 = -INFINITY;
    unsigned* const gs0 = gcut + qbase + wv * 32 + mrow;        // mt=0 query slot
    unsigned* const gs1 = gcut + qbase + wv * 32 + 16 + mrow;   // mt=1 query slot

    const char* BsB = (const char*)Bs;

    // ---- stage first chunk ----
    int c = blockIdx.x;
    {
        const char* src = bprep + (size_t)c * CH_BYTES;
        #pragma unroll
        for (int i = 0; i < 8; ++i) {
            int s = tid + i * 256;
            async_cp16(src + s * 16, (void*)(BsB + s * 16));
        }
    }
    __syncthreads();   // Bs ready

    for (int it = 0; it < CHUNKS_PER_BLK; ++it) {
        const int nbase = c * BC;
        const int cn    = c + PCH;
        const bool more = (it + 1) < CHUNKS_PER_BLK;

        // ---- publish team 16th-best lower bounds, fetch global cutoffs ----
        // (one device-scope RMW per team; latency hides under the MFMA phase)
        float p0 = my0;
        p0 = fmaxf(p0, __shfl_xor(p0, 16)); p0 = fmaxf(p0, __shfl_xor(p0, 32));
        float p1 = my1;
        p1 = fmaxf(p1, __shfl_xor(p1, 16)); p1 = fmaxf(p1, __shfl_xor(p1, 32));
        unsigned e0 = ENC_NEGINF, e1 = ENC_NEGINF;
        if (quad == 0) e0 = atomicMax(gs0, map_f32(p0));
        if (quad == 1) e1 = atomicMax(gs1, map_f32(p1));

        // ---- m2la for this lane's 16 blobs (2 float4 per nt, L1-broadcast) ----
        float4 mlA[4], mlB[4];
        #pragma unroll
        for (int nt = 0; nt < 4; ++nt) {
            const float4* mp = (const float4*)&m2la[(size_t)(nbase + nt * 16 + quad * 4) * 2];
            mlA[nt] = mp[0]; mlB[nt] = mp[1];
        }

        // ---- MFMA (swapped): acc[mt][nt] = D[blob][query] fragments ----
        f32x4 acc[2][4];
        #pragma unroll
        for (int nt = 0; nt < 4; ++nt) {
            bf16x8 bh[4], bl[4];
            #pragma unroll
            for (int ks = 0; ks < 4; ++ks) {
                bh[ks] = *(const bf16x8*)(BsB + nt * 4096 + ks * 1024 + lane * 16);
                bl[ks] = *(const bf16x8*)(BsB + SPLIT_OFF + nt * 4096 + ks * 1024 + lane * 16);
            }
            #pragma unroll
            for (int mt = 0; mt < 2; ++mt) {
                f32x4 a = {0.0f, 0.0f, 0.0f, 0.0f};
                #pragma unroll
                for (int ks = 0; ks < 4; ++ks) {
                    a = __builtin_amdgcn_mfma_f32_16x16x32_bf16(bh[ks], ahi[mt][ks], a, 0, 0, 0);
                    a = __builtin_amdgcn_mfma_f32_16x16x32_bf16(bl[ks], ahi[mt][ks], a, 0, 0, 0);
                    a = __builtin_amdgcn_mfma_f32_16x16x32_bf16(bh[ks], alo[mt][ks], a, 0, 0, 0);
                }
                acc[mt][nt] = a;
            }
        }
        __syncthreads();   // B1: frag reads done; Bs reusable

        if (more) {
            const char* src = bprep + (size_t)cn * CH_BYTES;
            #pragma unroll
            for (int i = 0; i < 8; ++i) {
                int s = tid + i * 256;
                async_cp16(src + s * 16, (void*)(BsB + s * 16));
            }
        }

        // ---- broadcast global cutoffs to all team lanes ----
        unsigned ee0 = __shfl(e0, mrow);        // from quad-0 lane of the team
        unsigned ee1 = __shfl(e1, 16 + mrow);   // from quad-1 lane of the team
        const float gc0 = fmaxf(unmap_f32(ee0), p0);
        const float gc1 = fmaxf(unmap_f32(ee1), p1);

        // ---- transform + screen + survivor insertion, all in registers ----
        // mt = 0
        {
            float cut = fmaxf(my0, gc0);
            unsigned gm = 0u;
            #pragma unroll
            for (int nt = 0; nt < 4; ++nt) {
                float m2_0 = mlA[nt].x, la_0 = mlA[nt].y;
                float m2_1 = mlA[nt].z, la_1 = mlA[nt].w;
                float m2_2 = mlB[nt].x, la_2 = mlB[nt].y;
                float m2_3 = mlB[nt].z, la_3 = mlB[nt].w;
                float s0 = nhit * (acc[0][nt][0] + m2_0) + la_0;
                float s1 = nhit * (acc[0][nt][1] + m2_1) + la_1;
                float s2 = nhit * (acc[0][nt][2] + m2_2) + la_2;
                float s3 = nhit * (acc[0][nt][3] + m2_3) + la_3;
                acc[0][nt][0] = s0; acc[0][nt][1] = s1;
                acc[0][nt][2] = s2; acc[0][nt][3] = s3;
                if (s0 > cut) gm |= 1u << (nt * 4);
                if (s1 > cut) gm |= 1u << (nt * 4 + 1);
                if (s2 > cut) gm |= 1u << (nt * 4 + 2);
                if (s3 > cut) gm |= 1u << (nt * 4 + 3);
            }
            while (__any(gm != 0u)) {
                if (gm) {
                    int i = __ffs(gm) - 1; gm &= gm - 1u;
                    float s = mux16(acc[0], i);
                    if (s > cut) {
                        ins16(ts0, ti0, my0, s, nbase + (i >> 2) * 16 + quad * 4 + (i & 3));
                        cut = fmaxf(my0, gc0);
                    }
                }
            }
        }
        // mt = 1
        {
            float cut = fmaxf(my1, gc1);
            unsigned gm = 0u;
            #pragma unroll
            for (int nt = 0; nt < 4; ++nt) {
                float m2_0 = mlA[nt].x, la_0 = mlA[nt].y;
                float m2_1 = mlA[nt].z, la_1 = mlA[nt].w;
                float m2_2 = mlB[nt].x, la_2 = mlB[nt].y;
                float m2_3 = mlB[nt].z, la_3 = mlB[nt].w;
                float s0 = nhit * (acc[1][nt][0] + m2_0) + la_0;
                float s1 = nhit * (acc[1][nt][1] + m2_1) + la_1;
                float s2 = nhit * (acc[1][nt][2] + m2_2) + la_2;
                float s3 = nhit * (acc[1][nt][3] + m2_3) + la_3;
                acc[1][nt][0] = s0; acc[1][nt][1] = s1;
                acc[1][nt][2] = s2; acc[1][nt][3] = s3;
                if (s0 > cut) gm |= 1u << (nt * 4);
                if (s1 > cut) gm |= 1u << (nt * 4 + 1);
                if (s2 > cut) gm |= 1u << (nt * 4 + 2);
                if (s3 > cut) gm |= 1u << (nt * 4 + 3);
            }
            while (__any(gm != 0u)) {
                if (gm) {
                    int i = __ffs(gm) - 1; gm &= gm - 1u;
                    float s = mux16(acc[1], i);
                    if (s > cut) {
                        ins16(ts1, ti1, my1, s, nbase + (i >> 2) * 16 + quad * 4 + (i & 3));
                        cut = fmaxf(my1, gc1);
                    }
                }
            }
        }

        __syncthreads();   // B2: staged Bs ready for next iter (vmcnt drained)
        c = cn;
    }

    // ---- team merge: top-16 of the 4 lanes' 64 entries, per mt ----
    #pragma unroll
    for (int mt = 0; mt < 2; ++mt) {
        u64 k[16];
        #pragma unroll
        for (int i = 0; i < 16; ++i) {
            float  tsv = (mt == 0) ? ts0[i] : ts1[i];
            int    tiv = (mt == 0) ? ti0[i] : ti1[i];
            k[i] = ((u64)map_f32(tsv) << 32) | (u64)(0xFFFFFFFFu - (unsigned)tiv);
        }
        u64 outv[4];
        #pragma unroll
        for (int r = 0; r < 16; ++r) {
            u64 m = k[0];
            #pragma unroll
            for (int j = 1; j < 16; ++j) if (k[j] > m) m = k[j];
            u64 o = shflxor64(m, 16); if (o > m) m = o;
            o = shflxor64(m, 32);     if (o > m) m = o;
            #pragma unroll
            for (int j = 0; j < 16; ++j) if (k[j] == m) k[j] = 0ull;   // idx-tagged: unique
            if ((r & 3) == quad) outv[r >> 2] = m;
        }
        u64* dst = cand + ((size_t)blockIdx.x * BQ + qbase + wv * 32 + mt * 16 + mrow) * KSEL;
        #pragma unroll
        for (int j = 0; j < 4; ++j)
            dst[quad + 4 * j] = outv[j];
    }
}

// ---------------- global merge + exact recompute + compositing ----------------
__global__ __launch_bounds__(256)
void merge_composite_kernel(const float* __restrict__ query,
                            const float* __restrict__ mu,
                            const float* __restrict__ log_var,
                            const float* __restrict__ raw_alpha,
                            const float* __restrict__ features,
                            const float* __restrict__ log_tau_p,
                            const u64* __restrict__ cand,
                            float* __restrict__ out)
{
    const int q   = blockIdx.x;
    const int tid = threadIdx.x;
    const int wv = tid >> 6, lane = tid & 63;

    __shared__ u64   wtop[4 * KSEL];
    __shared__ int   sel[KSEL];
    __shared__ float w_sh[KSEL];
    __shared__ float mah[KSEL];
    __shared__ float alp[KSEL];

    // 1024 keys in [stripe][query][16] layout: each wave owns 256 consecutive ids
    u64 k[4];
    #pragma unroll
    for (int r = 0; r < 4; ++r) {
        int g = wv * 256 + r * 64 + lane;
        k[r] = cand[((size_t)(g >> 4) * BQ + q) * KSEL + (g & 15)];
    }

    // wave-local top-16 (no barriers)
    for (int r = 0; r < KSEL; ++r) {
        u64 m = k[0];
        #pragma unroll
        for (int j = 1; j < 4; ++j) if (k[j] > m) m = k[j];
        #pragma unroll
        for (int off = 32; off > 0; off >>= 1) {
            unsigned hi = __shfl_xor((unsigned)(m >> 32), off);
            unsigned lo = __shfl_xor((unsigned)(m & 0xFFFFFFFFu), off);
            u64 o = ((u64)hi << 32) | lo;
            if (o > m) m = o;
        }
        if (lane == 0) wtop[wv * KSEL + r] = m;
        #pragma unroll
        for (int j = 0; j < 4; ++j) if (k[j] == m) k[j] = 0ull;  // keys unique
    }
    __syncthreads();

    // wave 0: merge 64 -> 16 (shuffle argmax rounds)
    if (wv == 0) {
        u64 kk = wtop[lane];
        for (int r = 0; r < KSEL; ++r) {
            u64 m = kk;
            #pragma unroll
            for (int off = 32; off > 0; off >>= 1) {
                unsigned hi = __shfl_xor((unsigned)(m >> 32), off);
                unsigned lo = __shfl_xor((unsigned)(m & 0xFFFFFFFFu), off);
                u64 o = ((u64)hi << 32) | lo;
                if (o > m) m = o;
            }
            if (kk == m) kk = 0ull;
            if (lane == 0)
                sel[r] = (int)(0xFFFFFFFFu - (unsigned)(m & 0xFFFFFFFFull));
        }
    }
    __syncthreads();

    // exact mahal per selected blob (direct gathered form, like reference)
    for (int r = wv; r < KSEL; r += 4) {
        int bi = sel[r];
        float qd = query[(size_t)q * DS + lane];
        float mv = mu[(size_t)bi * DS + lane];
        float d  = qd - mv;
        float t  = d * d * expf(-log_var[(size_t)bi * DS + lane]);
        #pragma unroll
        for (int off = 32; off > 0; off >>= 1) t += __shfl_down(t, off);
        if (lane == 0) {
            mah[r] = t;
            alp[r] = 1.0f / (1.0f + expf(-raw_alpha[bi]));
        }
    }
    __syncthreads();

    if (tid == 0) {
        float tau = expf(log_tau_p[0]);
        float cap = 0.3f / 16.0f;
        float logT = 0.0f;
        for (int r = 0; r < KSEL; ++r) {
            float K   = expf(-0.5f * mah[r] / tau);
            float eff = fminf(alp[r] * K, cap);
            w_sh[r]   = eff * expf(logT);
            logT     += log1pf(-fminf(eff, 1.0f - 1e-6f));
        }
        out[(size_t)BQ * DF + q] = expf(logT);
    }
    __syncthreads();

    {
        float a = 0.0f;
        #pragma unroll
        for (int r = 0; r < KSEL; ++r)
            a += w_sh[r] * features[(size_t)sel[r] * DF + tid];
        out[(size_t)q * DF + tid] = a;
    }
}

// ---------------- launch ----------------
extern "C" void kernel_launch(void* const* d_in, const int* in_sizes, int n_in,
                              void* d_out, int out_size, void* d_ws, size_t ws_size,
                              hipStream_t stream)
{
    (void)in_sizes; (void)n_in; (void)out_size; (void)ws_size;
    const float* query     = (const float*)d_in[0];
    const float* mu        = (const float*)d_in[1];
    const float* log_var   = (const float*)d_in[2];
    const float* raw_alpha = (const float*)d_in[3];
    const float* features  = (const float*)d_in[4];
    const float* log_tau   = (const float*)d_in[5];
    float* out = (float*)d_out;

    // ws layout: Bprep 64 MB | m2la 1 MB | cand 8 MB
    char*  bprep = (char*)d_ws;
    float* m2la  = (float*)((char*)d_ws + (size_t)NCHUNK * CH_BYTES);
    u64*   cand  = (u64*)((char*)d_ws + (size_t)NCHUNK * CH_BYTES + (size_t)NB * 2 * 4);
    // global per-query cutoffs: borrow the t_residual tail of `out` (4 KB);
    // merge_composite_kernel fully overwrites it afterwards.
    unsigned* gcut = (unsigned*)(out + (size_t)BQ * DF);

    prep_kernel<<<(NB * 8) / 256, 256, 0, stream>>>(mu, log_var, raw_alpha, bprep, m2la, gcut);

    dim3 g2(PCH, BQ / QT);
    score_topk_kernel<<<g2, 256, 0, stream>>>(query, bprep, m2la, log_tau, cand, gcut);

    merge_composite_kernel<<<BQ, 256, 0, stream>>>(query, mu, log_var, raw_alpha,
                                                   features, log_tau, cand, out);
}

// Round 9
// 557.705 us; speedup vs baseline: 3.2509x; 1.1156x over previous
//
#include <hip/hip_runtime.h>
#include <math.h>

// ---------------- problem constants ----------------
#define BQ    1024
#define NB    131072
#define DS    64
#define DF    256
#define KSEL  16

// ---------------- score kernel tiling ----------------
#define QT    128        // queries per block (4 waves x 32)
#define BC    64         // blobs per chunk
#define PCH   64         // chunk stripes (grid.x)
#define NCHUNK (NB / BC)             // 2048
#define CHUNKS_PER_BLK (NCHUNK/PCH)  // 32

// Bprep layout per chunk: [split(2)][ntile(4)][kstep(4)][lane(64)][16B] = 32 KB
#define CH_BYTES   32768
#define SPLIT_OFF  16384

typedef __bf16 bf16x8 __attribute__((ext_vector_type(8)));
typedef float  f32x4  __attribute__((ext_vector_type(4)));
typedef unsigned long long u64;

#define ENC_NEGINF 0x007FFFFFu   // map_f32(-inf)

__device__ __forceinline__ unsigned map_f32(float s) {
    unsigned u = __float_as_uint(s);
    return (u & 0x80000000u) ? ~u : (u | 0x80000000u);
}

__device__ __forceinline__ float unmap_f32(unsigned e) {
    return __uint_as_float((e & 0x80000000u) ? (e & 0x7FFFFFFFu) : ~e);
}

__device__ __forceinline__ void async_cp16(const void* g, void* l) {
    __builtin_amdgcn_global_load_lds(
        (const __attribute__((address_space(1))) unsigned int*)g,
        (__attribute__((address_space(3))) unsigned int*)l, 16, 0, 0);
}

// ---------------- fused preprocess: fragments + folded affine term ----------------
// m2a[blob] = m2 + la/nhit  (so score s = nhit * (acc + m2a)); halves the
// per-iter metadata traffic in the score kernel and removes 32 FMA/lane/iter.
__global__ __launch_bounds__(256)
void prep_kernel(const float* __restrict__ mu,
                 const float* __restrict__ log_var,
                 const float* __restrict__ raw_alpha,
                 const float* __restrict__ log_tau_p,
                 char* __restrict__ bprep,
                 float* __restrict__ m2a,
                 unsigned* __restrict__ gcut)
{
    int gid  = blockIdx.x * 256 + threadIdx.x;   // NB*8 = 2^20 threads
    if (gid < BQ) gcut[gid] = ENC_NEGINF;        // re-init global cutoffs each launch
    int blob = gid >> 3;
    int dd   = gid & 7;

    const float* mrow = mu      + (size_t)blob * DS + dd * 8;
    const float* vrow = log_var + (size_t)blob * DS + dd * 8;
    float4 ma = ((const float4*)mrow)[0], mb = ((const float4*)mrow)[1];
    float4 va = ((const float4*)vrow)[0], vb = ((const float4*)vrow)[1];
    float m[8] = {ma.x, ma.y, ma.z, ma.w, mb.x, mb.y, mb.z, mb.w};
    float lv[8] = {va.x, va.y, va.z, va.w, vb.x, vb.y, vb.z, vb.w};

    bf16x8 hiv, liv, hmv, lmv;
    float p = 0.0f;
    #pragma unroll
    for (int j = 0; j < 8; ++j) {
        float iv = __expf(-lv[j]);
        float mv = m[j] * iv;
        p += m[j] * mv;
        __bf16 h1 = (__bf16)iv;  hiv[j] = h1; liv[j] = (__bf16)(iv - (float)h1);
        __bf16 h2 = (__bf16)mv;  hmv[j] = h2; lmv[j] = (__bf16)(mv - (float)h2);
    }
    p += __shfl_xor(p, 1);
    p += __shfl_xor(p, 2);
    p += __shfl_xor(p, 4);

    int c  = blob >> 6;
    int nt = (blob >> 4) & 3;
    int bl = blob & 15;
    int lane  = (dd & 3) * 16 + bl;
    int ks_iv = dd >> 2;            // k = dd*8      (iv rows: k in [0,64))
    int ks_mv = 2 + (dd >> 2);      // k = 64+dd*8   (mu*iv rows)
    size_t b_iv = (size_t)c * CH_BYTES + nt * 4096 + ks_iv * 1024 + lane * 16;
    size_t b_mv = (size_t)c * CH_BYTES + nt * 4096 + ks_mv * 1024 + lane * 16;
    *(bf16x8*)(bprep + b_iv)             = hiv;
    *(bf16x8*)(bprep + b_iv + SPLIT_OFF) = liv;
    *(bf16x8*)(bprep + b_mv)             = hmv;
    *(bf16x8*)(bprep + b_mv + SPLIT_OFF) = lmv;

    if (dd == 0) {
        float la = -log1pf(__expf(-raw_alpha[blob]));     // log sigmoid
        float inv_nhit = -2.0f * __expf(log_tau_p[0]);    // 1/nhit
        m2a[blob] = p + la * inv_nhit;
    }
}

// ---------------- register top-16 insertion (tree argmin, unsorted) ----------------
__device__ __forceinline__ void ins16(float (&ts)[16], int (&ti)[16],
                                      float& mymin, float s, int idx)
{
    float v0[8]; int j0[8];
    #pragma unroll
    for (int i = 0; i < 8; ++i) {
        bool b = ts[2*i+1] < ts[2*i];
        v0[i] = b ? ts[2*i+1] : ts[2*i];
        j0[i] = (i << 1) | (b ? 1 : 0);
    }
    float v1[4]; int j1[4];
    #pragma unroll
    for (int i = 0; i < 4; ++i) {
        bool b = v0[2*i+1] < v0[2*i];
        v1[i] = b ? v0[2*i+1] : v0[2*i];
        j1[i] = b ? j0[2*i+1] : j0[2*i];
    }
    float v2[2]; int j2[2];
    #pragma unroll
    for (int i = 0; i < 2; ++i) {
        bool b = v1[2*i+1] < v1[2*i];
        v2[i] = b ? v1[2*i+1] : v1[2*i];
        j2[i] = b ? j1[2*i+1] : j1[2*i];
    }
    int am = (v2[1] < v2[0]) ? j2[1] : j2[0];
    #pragma unroll
    for (int i = 0; i < 16; ++i) {
        bool b = (i == am);
        ts[i] = b ? s : ts[i];
        ti[i] = b ? idx : ti[i];
    }
    float n0[8];
    #pragma unroll
    for (int i = 0; i < 8; ++i) n0[i] = fminf(ts[2*i], ts[2*i+1]);
    float n1[4];
    #pragma unroll
    for (int i = 0; i < 4; ++i) n1[i] = fminf(n0[2*i], n0[2*i+1]);
    mymin = fminf(fminf(n1[0], n1[1]), fminf(n1[2], n1[3]));
}

// static 16:1 mux over acc[4] f32x4 (no runtime array indexing -> no scratch)
__device__ __forceinline__ float mux16(const f32x4 (&a)[4], int i)
{
    float v = a[0][0];
    v = (i == 1)  ? a[0][1] : v;  v = (i == 2)  ? a[0][2] : v;  v = (i == 3)  ? a[0][3] : v;
    v = (i == 4)  ? a[1][0] : v;  v = (i == 5)  ? a[1][1] : v;  v = (i == 6)  ? a[1][2] : v;
    v = (i == 7)  ? a[1][3] : v;  v = (i == 8)  ? a[2][0] : v;  v = (i == 9)  ? a[2][1] : v;
    v = (i == 10) ? a[2][2] : v;  v = (i == 11) ? a[2][3] : v;  v = (i == 12) ? a[3][0] : v;
    v = (i == 13) ? a[3][1] : v;  v = (i == 14) ? a[3][2] : v;  v = (i == 15) ? a[3][3] : v;
    return v;
}

__device__ __forceinline__ u64 shflxor64(u64 m, int mask)
{
    unsigned hi = __shfl_xor((unsigned)(m >> 32), mask);
    unsigned lo = __shfl_xor((unsigned)(m & 0xFFFFFFFFu), mask);
    return ((u64)hi << 32) | lo;
}

// ---------------- score + top-k kernel ----------------
// Swapped MFMA (D[blob][query]); register-resident screen/top-16 (R8 verified).
// New this round: (a) iter-0 direct fill (16 scores = the lane's top-16-of-16;
// no ins16 storm), (b) folded-affine screen u = acc + A, survive iff u < T
// where T = cut/nhit (nhit < 0 flips the inequality).
__global__ __launch_bounds__(256, 2)
void score_topk_kernel(const float* __restrict__ query,
                       const char* __restrict__ bprep,
                       const float* __restrict__ m2a,
                       const float* __restrict__ log_tau_p,
                       u64* __restrict__ cand,
                       unsigned* __restrict__ gcut)
{
    __shared__ __align__(16) short Bs[CH_BYTES / 2];   // 32 KB fragment buffer

    const int tid   = threadIdx.x;
    const int lane  = tid & 63;
    const int quad  = lane >> 4;
    const int mrow  = lane & 15;
    const int wv    = tid >> 6;
    const int qbase = blockIdx.y * QT;

    const float nhit     = -0.5f * expf(-log_tau_p[0]);
    const float inv_nhit = 1.0f / nhit;                 // negative

    // ---- build persistent query fragments (hi+lo) in registers ----
    bf16x8 ahi[2][4], alo[2][4];
    #pragma unroll
    for (int mt = 0; mt < 2; ++mt) {
        const float* qrow = query + (size_t)(qbase + wv * 32 + mt * 16 + mrow) * DS;
        #pragma unroll
        for (int ks = 0; ks < 4; ++ks) {
            int kq = ks * 32 + quad * 8;
            int d0 = kq & 63;
            bool lin = kq >= 64;
            bf16x8 h, l;
            #pragma unroll
            for (int j = 0; j < 8; ++j) {
                float v = qrow[d0 + j];
                float x = lin ? (-2.0f * v) : (v * v);
                __bf16 hb = (__bf16)x;
                h[j] = hb;
                l[j] = (__bf16)(x - (float)hb);
            }
            ahi[mt][ks] = h; alo[mt][ks] = l;
        }
    }

    // ---- per-lane top-16 state for the lane's two queries ----
    float ts0[16], ts1[16]; int ti0[16], ti1[16];
    #pragma unroll
    for (int i = 0; i < 16; ++i) {
        ts0[i] = -INFINITY; ti0[i] = 0;
        ts1[i] = -INFINITY; ti1[i] = 0;
    }
    float my0 = -INFINITY, my1 = -INFINITY;
    unsigned* const gs0 = gcut + qbase + wv * 32 + mrow;        // mt=0 query slot
    unsigned* const gs1 = gcut + qbase + wv * 32 + 16 + mrow;   // mt=1 query slot

    const char* BsB = (const char*)Bs;

    // ---- stage first chunk ----
    int c = blockIdx.x;
    {
        const char* src = bprep + (size_t)c * CH_BYTES;
        #pragma unroll
        for (int i = 0; i < 8; ++i) {
            int s = tid + i * 256;
            async_cp16(src + s * 16, (void*)(BsB + s * 16));
        }
    }
    __syncthreads();   // Bs ready

    for (int it = 0; it < CHUNKS_PER_BLK; ++it) {
        const int nbase = c * BC;
        const int cn    = c + PCH;
        const bool more = (it + 1) < CHUNKS_PER_BLK;

        // ---- publish team 16th-best lower bounds, fetch global cutoffs ----
        float p0 = my0;
        p0 = fmaxf(p0, __shfl_xor(p0, 16)); p0 = fmaxf(p0, __shfl_xor(p0, 32));
        float p1 = my1;
        p1 = fmaxf(p1, __shfl_xor(p1, 16)); p1 = fmaxf(p1, __shfl_xor(p1, 32));
        unsigned e0 = ENC_NEGINF, e1 = ENC_NEGINF;
        if (quad == 0) e0 = atomicMax(gs0, map_f32(p0));
        if (quad == 1) e1 = atomicMax(gs1, map_f32(p1));

        // ---- A-terms for this lane's 16 blobs (one float4 per nt) ----
        f32x4 aA[4];
        #pragma unroll
        for (int nt = 0; nt < 4; ++nt)
            aA[nt] = *(const f32x4*)&m2a[(size_t)(nbase + nt * 16 + quad * 4)];

        // ---- MFMA (swapped): acc[mt][nt] = D[blob][query] fragments ----
        f32x4 acc[2][4];
        #pragma unroll
        for (int nt = 0; nt < 4; ++nt) {
            bf16x8 bh[4], bl[4];
            #pragma unroll
            for (int ks = 0; ks < 4; ++ks) {
                bh[ks] = *(const bf16x8*)(BsB + nt * 4096 + ks * 1024 + lane * 16);
                bl[ks] = *(const bf16x8*)(BsB + SPLIT_OFF + nt * 4096 + ks * 1024 + lane * 16);
            }
            #pragma unroll
            for (int mt = 0; mt < 2; ++mt) {
                f32x4 a = {0.0f, 0.0f, 0.0f, 0.0f};
                #pragma unroll
                for (int ks = 0; ks < 4; ++ks) {
                    a = __builtin_amdgcn_mfma_f32_16x16x32_bf16(bh[ks], ahi[mt][ks], a, 0, 0, 0);
                    a = __builtin_amdgcn_mfma_f32_16x16x32_bf16(bl[ks], ahi[mt][ks], a, 0, 0, 0);
                    a = __builtin_amdgcn_mfma_f32_16x16x32_bf16(bh[ks], alo[mt][ks], a, 0, 0, 0);
                }
                acc[mt][nt] = a;
            }
        }
        __syncthreads();   // B1: frag reads done; Bs reusable

        if (more) {
            const char* src = bprep + (size_t)cn * CH_BYTES;
            #pragma unroll
            for (int i = 0; i < 8; ++i) {
                int s = tid + i * 256;
                async_cp16(src + s * 16, (void*)(BsB + s * 16));
            }
        }

        if (it == 0) {
            // ---- iter-0 direct fill: top-16 of 16 scores = all of them ----
            #pragma unroll
            for (int nt = 0; nt < 4; ++nt)
                #pragma unroll
                for (int reg = 0; reg < 4; ++reg) {
                    int idx = nbase + nt * 16 + quad * 4 + reg;
                    float s0 = nhit * (acc[0][nt][reg] + aA[nt][reg]);
                    float s1 = nhit * (acc[1][nt][reg] + aA[nt][reg]);
                    ts0[nt * 4 + reg] = s0; ti0[nt * 4 + reg] = idx;
                    ts1[nt * 4 + reg] = s1; ti1[nt * 4 + reg] = idx;
                }
            float n0[8], n1[8];
            #pragma unroll
            for (int i = 0; i < 8; ++i) {
                n0[i] = fminf(ts0[2*i], ts0[2*i+1]);
                n1[i] = fminf(ts1[2*i], ts1[2*i+1]);
            }
            my0 = fminf(fminf(fminf(n0[0], n0[1]), fminf(n0[2], n0[3])),
                        fminf(fminf(n0[4], n0[5]), fminf(n0[6], n0[7])));
            my1 = fminf(fminf(fminf(n1[0], n1[1]), fminf(n1[2], n1[3])),
                        fminf(fminf(n1[4], n1[5]), fminf(n1[6], n1[7])));
        } else {
            // ---- broadcast global cutoffs to all team lanes ----
            unsigned ee0 = __shfl(e0, mrow);        // from quad-0 lane of the team
            unsigned ee1 = __shfl(e1, 16 + mrow);   // from quad-1 lane of the team
            const float gc0 = fmaxf(unmap_f32(ee0), p0);
            const float gc1 = fmaxf(unmap_f32(ee1), p1);

            // ---- folded-affine screen: u = acc + A; survive iff u < T ----
            // mt = 0
            {
                float cut = fmaxf(my0, gc0);
                float T = cut * inv_nhit;
                T = T + fabsf(T) * 2e-7f;           // 1-ulp safety margin
                unsigned gm = 0u;
                #pragma unroll
                for (int nt = 0; nt < 4; ++nt) {
                    float u0 = acc[0][nt][0] + aA[nt][0];
                    float u1 = acc[0][nt][1] + aA[nt][1];
                    float u2 = acc[0][nt][2] + aA[nt][2];
                    float u3 = acc[0][nt][3] + aA[nt][3];
                    acc[0][nt][0] = u0; acc[0][nt][1] = u1;
                    acc[0][nt][2] = u2; acc[0][nt][3] = u3;
                    if (u0 < T) gm |= 1u << (nt * 4);
                    if (u1 < T) gm |= 1u << (nt * 4 + 1);
                    if (u2 < T) gm |= 1u << (nt * 4 + 2);
                    if (u3 < T) gm |= 1u << (nt * 4 + 3);
                }
                while (__any(gm != 0u)) {
                    if (gm) {
                        int i = __ffs(gm) - 1; gm &= gm - 1u;
                        float s = nhit * mux16(acc[0], i);
                        if (s > cut) {
                            ins16(ts0, ti0, my0, s, nbase + (i >> 2) * 16 + quad * 4 + (i & 3));
                            cut = fmaxf(my0, gc0);
                            T = cut * inv_nhit;
                            T = T + fabsf(T) * 2e-7f;
                        }
                    }
                }
            }
            // mt = 1
            {
                float cut = fmaxf(my1, gc1);
                float T = cut * inv_nhit;
                T = T + fabsf(T) * 2e-7f;
                unsigned gm = 0u;
                #pragma unroll
                for (int nt = 0; nt < 4; ++nt) {
                    float u0 = acc[1][nt][0] + aA[nt][0];
                    float u1 = acc[1][nt][1] + aA[nt][1];
                    float u2 = acc[1][nt][2] + aA[nt][2];
                    float u3 = acc[1][nt][3] + aA[nt][3];
                    acc[1][nt][0] = u0; acc[1][nt][1] = u1;
                    acc[1][nt][2] = u2; acc[1][nt][3] = u3;
                    if (u0 < T) gm |= 1u << (nt * 4);
                    if (u1 < T) gm |= 1u << (nt * 4 + 1);
                    if (u2 < T) gm |= 1u << (nt * 4 + 2);
                    if (u3 < T) gm |= 1u << (nt * 4 + 3);
                }
                while (__any(gm != 0u)) {
                    if (gm) {
                        int i = __ffs(gm) - 1; gm &= gm - 1u;
                        float s = nhit * mux16(acc[1], i);
                        if (s > cut) {
                            ins16(ts1, ti1, my1, s, nbase + (i >> 2) * 16 + quad * 4 + (i & 3));
                            cut = fmaxf(my1, gc1);
                            T = cut * inv_nhit;
                            T = T + fabsf(T) * 2e-7f;
                        }
                    }
                }
            }
        }

        __syncthreads();   // B2: staged Bs ready for next iter (vmcnt drained)
        c = cn;
    }

    // ---- team merge: top-16 of the 4 lanes' 64 entries, per mt ----
    #pragma unroll
    for (int mt = 0; mt < 2; ++mt) {
        u64 k[16];
        #pragma unroll
        for (int i = 0; i < 16; ++i) {
            float  tsv = (mt == 0) ? ts0[i] : ts1[i];
            int    tiv = (mt == 0) ? ti0[i] : ti1[i];
            k[i] = ((u64)map_f32(tsv) << 32) | (u64)(0xFFFFFFFFu - (unsigned)tiv);
        }
        u64 outv[4];
        #pragma unroll
        for (int r = 0; r < 16; ++r) {
            u64 m = k[0];
            #pragma unroll
            for (int j = 1; j < 16; ++j) if (k[j] > m) m = k[j];
            u64 o = shflxor64(m, 16); if (o > m) m = o;
            o = shflxor64(m, 32);     if (o > m) m = o;
            #pragma unroll
            for (int j = 0; j < 16; ++j) if (k[j] == m) k[j] = 0ull;   // idx-tagged: unique
            if ((r & 3) == quad) outv[r >> 2] = m;
        }
        u64* dst = cand + ((size_t)blockIdx.x * BQ + qbase + wv * 32 + mt * 16 + mrow) * KSEL;
        #pragma unroll
        for (int j = 0; j < 4; ++j)
            dst[quad + 4 * j] = outv[j];
    }
}

// ---------------- global merge + exact recompute + compositing ----------------
__global__ __launch_bounds__(256)
void merge_composite_kernel(const float* __restrict__ query,
                            const float* __restrict__ mu,
                            const float* __restrict__ log_var,
                            const float* __restrict__ raw_alpha,
                            const float* __restrict__ features,
                            const float* __restrict__ log_tau_p,
                            const u64* __restrict__ cand,
                            float* __restrict__ out)
{
    const int q   = blockIdx.x;
    const int tid = threadIdx.x;
    const int wv = tid >> 6, lane = tid & 63;

    __shared__ u64   wtop[4 * KSEL];
    __shared__ int   sel[KSEL];
    __shared__ float w_sh[KSEL];
    __shared__ float mah[KSEL];
    __shared__ float alp[KSEL];

    // 1024 keys in [stripe][query][16] layout: each wave owns 256 consecutive ids
    u64 k[4];
    #pragma unroll
    for (int r = 0; r < 4; ++r) {
        int g = wv * 256 + r * 64 + lane;
        k[r] = cand[((size_t)(g >> 4) * BQ + q) * KSEL + (g & 15)];
    }

    // wave-local top-16 (no barriers)
    for (int r = 0; r < KSEL; ++r) {
        u64 m = k[0];
        #pragma unroll
        for (int j = 1; j < 4; ++j) if (k[j] > m) m = k[j];
        #pragma unroll
        for (int off = 32; off > 0; off >>= 1) {
            unsigned hi = __shfl_xor((unsigned)(m >> 32), off);
            unsigned lo = __shfl_xor((unsigned)(m & 0xFFFFFFFFu), off);
            u64 o = ((u64)hi << 32) | lo;
            if (o > m) m = o;
        }
        if (lane == 0) wtop[wv * KSEL + r] = m;
        #pragma unroll
        for (int j = 0; j < 4; ++j) if (k[j] == m) k[j] = 0ull;  // keys unique
    }
    __syncthreads();

    // wave 0: merge 64 -> 16 (shuffle argmax rounds)
    if (wv == 0) {
        u64 kk = wtop[lane];
        for (int r = 0; r < KSEL; ++r) {
            u64 m = kk;
            #pragma unroll
            for (int off = 32; off > 0; off >>= 1) {
                unsigned hi = __shfl_xor((unsigned)(m >> 32), off);
                unsigned lo = __shfl_xor((unsigned)(m & 0xFFFFFFFFu), off);
                u64 o = ((u64)hi << 32) | lo;
                if (o > m) m = o;
            }
            if (kk == m) kk = 0ull;
            if (lane == 0)
                sel[r] = (int)(0xFFFFFFFFu - (unsigned)(m & 0xFFFFFFFFull));
        }
    }
    __syncthreads();

    // exact mahal per selected blob (direct gathered form, like reference)
    for (int r = wv; r < KSEL; r += 4) {
        int bi = sel[r];
        float qd = query[(size_t)q * DS + lane];
        float mv = mu[(size_t)bi * DS + lane];
        float d  = qd - mv;
        float t  = d * d * expf(-log_var[(size_t)bi * DS + lane]);
        #pragma unroll
        for (int off = 32; off > 0; off >>= 1) t += __shfl_down(t, off);
        if (lane == 0) {
            mah[r] = t;
            alp[r] = 1.0f / (1.0f + expf(-raw_alpha[bi]));
        }
    }
    __syncthreads();

    if (tid == 0) {
        float tau = expf(log_tau_p[0]);
        float cap = 0.3f / 16.0f;
        float logT = 0.0f;
        for (int r = 0; r < KSEL; ++r) {
            float K   = expf(-0.5f * mah[r] / tau);
            float eff = fminf(alp[r] * K, cap);
            w_sh[r]   = eff * expf(logT);
            logT     += log1pf(-fminf(eff, 1.0f - 1e-6f));
        }
        out[(size_t)BQ * DF + q] = expf(logT);
    }
    __syncthreads();

    {
        float a = 0.0f;
        #pragma unroll
        for (int r = 0; r < KSEL; ++r)
            a += w_sh[r] * features[(size_t)sel[r] * DF + tid];
        out[(size_t)q * DF + tid] = a;
    }
}

// ---------------- launch ----------------
extern "C" void kernel_launch(void* const* d_in, const int* in_sizes, int n_in,
                              void* d_out, int out_size, void* d_ws, size_t ws_size,
                              hipStream_t stream)
{
    (void)in_sizes; (void)n_in; (void)out_size; (void)ws_size;
    const float* query     = (const float*)d_in[0];
    const float* mu        = (const float*)d_in[1];
    const float* log_var   = (const float*)d_in[2];
    const float* raw_alpha = (const float*)d_in[3];
    const float* features  = (const float*)d_in[4];
    const float* log_tau   = (const float*)d_in[5];
    float* out = (float*)d_out;

    // ws layout: Bprep 64 MB | m2a 0.5 MB (1 MB reserved) | cand 8 MB
    char*  bprep = (char*)d_ws;
    float* m2a   = (float*)((char*)d_ws + (size_t)NCHUNK * CH_BYTES);
    u64*   cand  = (u64*)((char*)d_ws + (size_t)NCHUNK * CH_BYTES + (size_t)NB * 2 * 4);
    // global per-query cutoffs: borrow the t_residual tail of `out` (4 KB);
    // merge_composite_kernel fully overwrites it afterwards.
    unsigned* gcut = (unsigned*)(out + (size_t)BQ * DF);

    prep_kernel<<<(NB * 8) / 256, 256, 0, stream>>>(mu, log_var, raw_alpha, log_tau,
                                                    bprep, m2a, gcut);

    dim3 g2(PCH, BQ / QT);
    score_topk_kernel<<<g2, 256, 0, stream>>>(query, bprep, m2a, log_tau, cand, gcut);

    merge_composite_kernel<<<BQ, 256, 0, stream>>>(query, mu, log_var, raw_alpha,
                                                   features, log_tau, cand, out);
}